// Round 2
// baseline (240.537 us; speedup 1.0000x reference)
//
#include <hip/hip_runtime.h>

// QuantizedBKCore: tridiagonal resolvent diagonal via two continued-fraction
// sweeps, bit-exact replication of the numpy float32/complex64 reference.
//
// Bit-exactness requirements (validated R1: absmax == 0):
//  - numpy complex64 division = Smith's algorithm (branch on |dr|>=|di|),
//    each op a separately-rounded IEEE f32 op -> fp contract OFF everywhere.
//  - rintf == np.rint (round half-even).
//  - recurrences evaluated in the reference's op order.
//
// R2 structure: SEG=32 (16 waves/CU vs 4 at SEG=128 — R1 was latency-bound at
// OccupancyPercent=10.9%, VALUBusy=21%, HBM=34%), R kept in registers
// (64 VGPRs, fully unrolled) instead of round-tripping 2x268 MB through d_out.
// WARM=64: two-step contraction factor <= 1/4 => 2^-64 analytic gap; the only
// empirically bit-validated margin.

#define SEG  32    // segment length per lane (R fits in 64 VGPRs)
#define WARM 64    // warmup steps from carry=0 before segment start

struct C2 { float r, i; };

// numpy CFLOAT_divide (Smith), numerator = (nr, 0), no FMA contraction.
__device__ __forceinline__ C2 npdiv(float nr, float dr, float di) {
  #pragma clang fp contract(off)
  const bool  b   = fabsf(dr) >= fabsf(di);
  const float num = b ? di : dr;
  const float den = b ? dr : di;
  const float rat = num / den;          // correctly-rounded IEEE div
  const float t   = num * rat;
  const float s   = den + t;            // mul + add, NOT fma
  const float scl = 1.0f / s;           // correctly-rounded IEEE div
  const float u   = nr * scl;
  const float m   = nr * rat;
  const float w   = m * scl;
  C2 o;
  o.r = b ? u : w;
  o.i = b ? -w : -u;                    // sign-of-product flip is exact
  return o;
}

// -(clip(h0_diag + fake_quantize(v), -10, 10)); exact op order.
__device__ __forceinline__ float neg_a(float vv, float hd) {
  #pragma clang fp contract(off)
  float q = rintf(vv);                         // v_rndne_f32 == np.rint
  q = fminf(fmaxf(q, -128.0f), 127.0f);
  float he = hd + q;
  he = fminf(fmaxf(he, -10.0f), 10.0f);
  return 0.0f - he;                            // Re(z - a)
}

// clip(+-100) -> rint -> clip(+-128); exact ops.
__device__ __forceinline__ float fq_out(float x) {
  #pragma clang fp contract(off)
  x = fminf(fmaxf(x, -100.0f), 100.0f);
  x = rintf(x);
  x = fminf(fmaxf(x, -128.0f), 127.0f);
  return x;
}

__global__ void __launch_bounds__(256, 4)
bk_kernel(const float* __restrict__ v,
          const float* __restrict__ hdiag,
          const float* __restrict__ hsub,
          const float* __restrict__ hsup,
          float2* __restrict__ out,      // (B,N) final values only
          int N, int segs_per_row, int B) {
  #pragma clang fp contract(off)
  const int g   = blockIdx.x * blockDim.x + threadIdx.x;
  const int row = g / segs_per_row;
  if (row >= B) return;
  const int seg = g - row * segs_per_row;
  const int s0  = seg * SEG;
  const int s1  = s0 + SEG;              // N % SEG == 0 (16384 / 32)

  const float* vr  = v   + (long)row * N;
  float2*      orr = out + (long)row * N;

  float cr, ci;
  int k;

  // ---------------- backward sweep: R[t] = R[s0+t] into registers ---------
  // R[N-1]=0; R[k-1] = c[k-1] / (z - a[k] - R[k])
  float Rr[SEG], Ri[SEG];
  cr = 0.0f; ci = 0.0f;                  // exact R[N-1] when j1 == N-1
  const int j1 = min(s1 - 1 + WARM, N - 1);
  #pragma unroll 8
  for (k = j1; k >= s1; --k) {           // warmup, contraction bit-merges carry
    const float negA = neg_a(vr[k], hdiag[k]);
    const float cc   = hsub[k-1] * hsup[k-1];
    const float dr   = negA - cr;        // ((0 - a) - Re carry)
    const float di   = 1.0f - ci;        // ((1 - 0) - Im carry)
    const C2 nc = npdiv(cc, dr, di);
    cr = nc.r; ci = nc.i;
  }
  Rr[SEG-1] = cr; Ri[SEG-1] = ci;        // R[s1-1]
  #pragma unroll
  for (int t = SEG - 1; t >= 1; --t) {
    k = s0 + t;
    const float negA = neg_a(vr[k], hdiag[k]);
    const float cc   = hsub[k-1] * hsup[k-1];
    const float dr   = negA - cr;
    const float di   = 1.0f - ci;
    const C2 nc = npdiv(cc, dr, di);
    cr = nc.r; ci = nc.i;
    Rr[t-1] = cr; Ri[t-1] = ci;
  }

  // ---------------- forward sweep + combine + store -----------------------
  // L[0]=0; L[k+1] = c[k] / (z - a[k] - L[k]);  G = 1 / (((z-a) - L) - R)
  cr = 0.0f; ci = 0.0f;                  // exact L[0] when k0 == 0
  const int k0 = max(s0 - WARM, 0);
  #pragma unroll 8
  for (k = k0; k < s0; ++k) {            // warmup
    const float negA = neg_a(vr[k], hdiag[k]);
    const float cc   = hsub[k] * hsup[k];
    const float dr   = negA - cr;
    const float di   = 1.0f - ci;
    const C2 nc = npdiv(cc, dr, di);
    cr = nc.r; ci = nc.i;
  }
  #pragma unroll
  for (int t = 0; t < SEG; ++t) {
    k = s0 + t;
    const float negA = neg_a(vr[k], hdiag[k]);
    const float drL = negA - cr;         // (z - a) - L  (real)
    const float diL = 1.0f - ci;         //              (imag)
    const float drf = drL - Rr[t];       // ... - R
    const float dif = diL - Ri[t];
    const C2 G = npdiv(1.0f, drf, dif);
    orr[k] = make_float2(fq_out(G.r), fq_out(G.i));
    if (t < SEG - 1) {                   // advance L (skip at seg end: c[N-1] OOB)
      const float cc = hsub[k] * hsup[k];
      const C2 nc = npdiv(cc, drL, diL);
      cr = nc.r; ci = nc.i;
    }
  }
}

extern "C" void kernel_launch(void* const* d_in, const int* in_sizes, int n_in,
                              void* d_out, int out_size, void* d_ws, size_t ws_size,
                              hipStream_t stream) {
  const float* v    = (const float*)d_in[0];
  const float* hd   = (const float*)d_in[1];
  const float* hsub = (const float*)d_in[2];
  const float* hsup = (const float*)d_in[3];
  const int N = in_sizes[1];
  const int B = in_sizes[0] / N;
  const int segs = N / SEG;                   // 512 for N=16384
  const long lanes = (long)B * segs;          // 262144 -> 4096 waves -> 16/CU
  const int block = 256;
  const int grid = (int)((lanes + block - 1) / block);
  bk_kernel<<<grid, block, 0, stream>>>(v, hd, hsub, hsup, (float2*)d_out, N, segs, B);
}